// Round 1
// baseline (441.344 us; speedup 1.0000x reference)
//
#include <hip/hip_runtime.h>
#include <math.h>

// Problem constants (fixed by setup_inputs): B=8 graphs, N=50000 nodes/graph,
// EPG=1e6 edges/graph, E=8e6, M=2048, num_passes=3.
#define GB    8
#define GN    50000
#define EPG   1000000
#define EDGES (GB*EPG)
#define NP    3

#define BW     4096           // bucket width (floats) -> 16KB LDS
#define NBUCK  13             // ceil(50000/4096); last bucket width 848
#define LBINS  (NBUCK*NBUCK)  // 169 (src-bucket x dst-bucket) bins per graph
#define NB2    (GB*LBINS)     // 1352 total 2D bins
#define STRIPE 4000           // edges per binning block
#define NQ     (STRIPE/4)     // 1000 quads
#define NBLKH  (EDGES/STRIPE) // 2000 binning blocks
#define BPG    (EPG/STRIPE)   // 250 blocks per graph
#define SCHUNK 6              // scan: 256*6 = 1536 >= NB2

// ============================ fast path ============================
// Structure: exact-packed 2D-binned records.
//  1. z_k       : zero gcur/cnt/nsq
//  2. count_k   : per-(sb,db) bin histogram (LDS combine, global atomic)
//  3. scan_k    : exclusive scan (even-rounded) over 1352 counts -> basea[]
//  4. fscatter_k: rank-in-LDS + reserve + scatter records EXACTLY packed:
//                 pos = basea[bin] + reserved + rank  (no CAP slack)
//                 rec.x = (dst_in_bucket<<12)|src_in_bucket, rec.y=log1pf(w)
//  5. accum_k x3: one block per (g,db,sb): stage src bucket (16KB) in LDS,
//                 gather = ds_read (no L2 divergence!), LDS-atomic into acc,
//                 write partials[g*13+db][sb].
//  6. reduce_k x3: sum 13 sb-partials per node; fused nsq on last pass.
//  7. final_k.
// Normalization telescopes: h3 = A^3 x / ||A^3 x||, so only final norm needed.

__global__ void z_k(int* __restrict__ gcur, int* __restrict__ cnt,
                    float* __restrict__ nsq) {
  for (int i = threadIdx.x; i < NB2; i += 256) { gcur[i] = 0; cnt[i] = 0; }
  if (threadIdx.x < GB) nsq[threadIdx.x] = 0.f;
}

__global__ __launch_bounds__(256) void count_k(
    const int* __restrict__ src, const int* __restrict__ dst,
    int* __restrict__ cnt) {
  __shared__ int lh[LBINS];
  for (int i = threadIdx.x; i < LBINS; i += 256) lh[i] = 0;
  __syncthreads();
  int blk = blockIdx.x;
  int s0 = blk * STRIPE;
  int g = blk / BPG;                  // stripe never crosses a graph
  int base = g * GN;
  const int4* d4 = (const int4*)(dst + s0);
  const int4* s4 = (const int4*)(src + s0);
#pragma unroll
  for (int u = 0; u < 4; ++u) {
    int q = threadIdx.x + 256 * u;
    if (q < NQ) {
      int4 d = d4[q]; int4 s = s4[q];
      atomicAdd(&lh[((s.x - base) >> 12) * NBUCK + ((d.x - base) >> 12)], 1);
      atomicAdd(&lh[((s.y - base) >> 12) * NBUCK + ((d.y - base) >> 12)], 1);
      atomicAdd(&lh[((s.z - base) >> 12) * NBUCK + ((d.z - base) >> 12)], 1);
      atomicAdd(&lh[((s.w - base) >> 12) * NBUCK + ((d.w - base) >> 12)], 1);
    }
  }
  __syncthreads();
  int gb = g * LBINS;
  for (int i = threadIdx.x; i < LBINS; i += 256) {
    int c = lh[i];
    if (c) atomicAdd(&cnt[gb + i], c);
  }
}

// Exclusive scan over NB2 counts, each rounded UP TO EVEN (so every bin's
// record range starts 16B-aligned for uint4 loads). Total pad <= NB2 recs.
__global__ void scan_k(const int* __restrict__ cnt, int* __restrict__ basea) {
  __shared__ int ps[256];
  int t = threadIdx.x;
  int loc[SCHUNK];
  int s = 0;
#pragma unroll
  for (int k = 0; k < SCHUNK; ++k) {
    int i = t * SCHUNK + k;
    int a = (i < NB2) ? ((cnt[i] + 1) & ~1) : 0;
    loc[k] = s;
    s += a;
  }
  ps[t] = s;
  __syncthreads();
  for (int o = 1; o < 256; o <<= 1) {
    int u = (t >= o) ? ps[t - o] : 0;
    __syncthreads();
    ps[t] += u;
    __syncthreads();
  }
  int ex = t ? ps[t - 1] : 0;
#pragma unroll
  for (int k = 0; k < SCHUNK; ++k) {
    int i = t * SCHUNK + k;
    if (i < NB2) basea[i] = ex + loc[k];
  }
  if (t == 255) basea[NB2] = ps[255];
}

// Fused bin+rank+reserve+scatter with exact bases:
//  phase 1: per-edge rank within (block,bin) via LDS hist (ranks in regs)
//  phase 2: lb[bin] = basea[bin] + atomicAdd(gcur[bin], c)
//  phase 3: re-read stripe (cache-resident) and write records at lb[bin]+rank.
__global__ __launch_bounds__(256) void fscatter_k(
    const int* __restrict__ src, const int* __restrict__ dst,
    const float* __restrict__ ew, const int* __restrict__ basea,
    int* __restrict__ gcur, uint2* __restrict__ recs) {
  __shared__ int lh[LBINS];
  __shared__ int lb[LBINS];
  for (int i = threadIdx.x; i < LBINS; i += 256) lh[i] = 0;
  __syncthreads();
  int blk = blockIdx.x;
  int s0 = blk * STRIPE;
  int g = blk / BPG;
  int base = g * GN, gb = g * LBINS;
  const int4* d4 = (const int4*)(dst + s0);
  const int4* s4 = (const int4*)(src + s0);
  const float4* w4 = (const float4*)(ew + s0);

  int rk[16];
#pragma unroll
  for (int u = 0; u < 4; ++u) {
    int q = threadIdx.x + 256 * u;
    if (q < NQ) {
      int4 d = d4[q]; int4 s = s4[q];
      rk[4 * u + 0] = atomicAdd(&lh[((s.x - base) >> 12) * NBUCK + ((d.x - base) >> 12)], 1);
      rk[4 * u + 1] = atomicAdd(&lh[((s.y - base) >> 12) * NBUCK + ((d.y - base) >> 12)], 1);
      rk[4 * u + 2] = atomicAdd(&lh[((s.z - base) >> 12) * NBUCK + ((d.z - base) >> 12)], 1);
      rk[4 * u + 3] = atomicAdd(&lh[((s.w - base) >> 12) * NBUCK + ((d.w - base) >> 12)], 1);
    }
  }
  __syncthreads();
  for (int i = threadIdx.x; i < LBINS; i += 256) {
    int c = lh[i];
    lb[i] = (c ? atomicAdd(&gcur[gb + i], c) : 0) + basea[gb + i];
  }
  __syncthreads();
#pragma unroll
  for (int u = 0; u < 4; ++u) {
    int q = threadIdx.x + 256 * u;
    if (q < NQ) {
      int4 d = d4[q]; int4 s = s4[q]; float4 w = w4[q];
      int dv[4] = {d.x, d.y, d.z, d.w};
      int sv[4] = {s.x, s.y, s.z, s.w};
      float wv[4] = {w.x, w.y, w.z, w.w};
#pragma unroll
      for (int k = 0; k < 4; ++k) {
        int dl = dv[k] - base;
        int sl = sv[k] - base;
        int l = (sl >> 12) * NBUCK + (dl >> 12);
        int pos = lb[l] + rk[4 * u + k];
        recs[pos] = make_uint2(((unsigned)(dl & (BW - 1)) << 12) |
                               (unsigned)(sl & (BW - 1)),
                               __float_as_uint(log1pf(wv[k])));
      }
    }
  }
}

// One block per (g, db, sb): src bucket staged in LDS (gather = ds_read),
// dst accumulated via LDS atomics; 2x uint4/iter over this bin's records.
__global__ __launch_bounds__(256) void accum_k(
    const uint2* __restrict__ recs, const int* __restrict__ basea,
    const int* __restrict__ cnt, const float* __restrict__ hin,
    float* __restrict__ partials) {
  __shared__ float sh[BW];          // staged src bucket
  __shared__ float acc[BW];         // dst accumulator
  int sb = blockIdx.x;              // src bucket [0,13)
  int gdb = blockIdx.y;             // g*13+db    [0,104)
  int g = gdb / NBUCK, db = gdb - g * NBUCK;
  int bin = g * LBINS + sb * NBUCK + db;

  float4 z = {0.f, 0.f, 0.f, 0.f};
  float4* a4 = (float4*)acc;
  for (int i = threadIdx.x; i < BW / 4; i += 256) a4[i] = z;
  int sw = GN - sb * BW; if (sw > BW) sw = BW;     // 848 for sb=12
  const float4* hp = (const float4*)(hin + (size_t)g * GN + (size_t)sb * BW);
  float4* sp = (float4*)sh;
  for (int i = threadIdx.x; i < sw / 4; i += 256) sp[i] = hp[i];

  int len = cnt[bin];
  const uint2* rb = recs + basea[bin];            // basea even -> 16B aligned
  __syncthreads();

  int np = len >> 1;                // uint4 count (2 recs each)
  const uint4* rp = (const uint4*)rb;
  int p = threadIdx.x;
  for (; p + 256 < np; p += 512) {
    uint4 r0 = rp[p];
    uint4 r1 = rp[p + 256];
    float a0 = sh[r0.x & (BW - 1)] * __uint_as_float(r0.y);
    float a1 = sh[r0.z & (BW - 1)] * __uint_as_float(r0.w);
    float a2 = sh[r1.x & (BW - 1)] * __uint_as_float(r1.y);
    float a3 = sh[r1.z & (BW - 1)] * __uint_as_float(r1.w);
    atomicAdd(&acc[r0.x >> 12], a0);
    atomicAdd(&acc[r0.z >> 12], a1);
    atomicAdd(&acc[r1.x >> 12], a2);
    atomicAdd(&acc[r1.z >> 12], a3);
  }
  if (p < np) {
    uint4 r0 = rp[p];
    atomicAdd(&acc[r0.x >> 12], sh[r0.x & (BW - 1)] * __uint_as_float(r0.y));
    atomicAdd(&acc[r0.z >> 12], sh[r0.z & (BW - 1)] * __uint_as_float(r0.w));
  }
  if ((len & 1) && threadIdx.x == 0) {
    uint2 a = rb[len - 1];
    atomicAdd(&acc[a.x >> 12], sh[a.x & (BW - 1)] * __uint_as_float(a.y));
  }
  __syncthreads();
  float4* po = (float4*)(partials + ((size_t)gdb * NBUCK + sb) * BW);
  for (int i = threadIdx.x; i < BW / 4; i += 256) po[i] = a4[i];
}

// Sum NBUCK sb-partials per node, float4-vectorized; optional fused ssq.
__global__ void reduce_k(const float* __restrict__ partials,
                         float* __restrict__ hout, float* __restrict__ nsq) {
  __shared__ float sm[GB];
  if (threadIdx.x < GB) sm[threadIdx.x] = 0.f;
  __syncthreads();
  int n4 = blockIdx.x * 256 + threadIdx.x;
  if (n4 < (GB * GN) / 4) {
    int n = n4 * 4;
    int g = n / GN;
    int dl = n - g * GN;
    int bucket = dl >> 12;
    int slot = dl & (BW - 1);
    const float4* p = (const float4*)(partials +
        ((size_t)(g * NBUCK + bucket) * NBUCK) * BW + slot);
    float4 s = {0.f, 0.f, 0.f, 0.f};
#pragma unroll
    for (int c = 0; c < NBUCK; ++c) {
      float4 t = p[c * (BW / 4)];
      s.x += t.x; s.y += t.y; s.z += t.z; s.w += t.w;
    }
    ((float4*)hout)[n4] = s;
    if (nsq) atomicAdd(&sm[g], s.x * s.x + s.y * s.y + s.z * s.z + s.w * s.w);
  }
  __syncthreads();
  if (nsq && threadIdx.x < GB && sm[threadIdx.x] != 0.f)
    unsafeAtomicAdd(&nsq[threadIdx.x], sm[threadIdx.x]);
}

// ============================ v1 fallback ============================

__global__ void init_k(const float* __restrict__ x, float* __restrict__ h_cur,
                       float* __restrict__ h_next, float* __restrict__ norms,
                       int BN, int n_norms) {
  int i = blockIdx.x * blockDim.x + threadIdx.x;
  int stride = gridDim.x * blockDim.x;
  for (int j = i; j < BN; j += stride) { h_cur[j] = x[j]; h_next[j] = 0.f; }
  if (i < n_norms) norms[i] = 0.f;
}

__global__ void edge_k(const int* __restrict__ src, const int* __restrict__ dst,
                       const float* __restrict__ ew, const float* __restrict__ h_in,
                       float* __restrict__ h_out, int E4, int E) {
  int i = blockIdx.x * blockDim.x + threadIdx.x;
  int stride = gridDim.x * blockDim.x;
  const int4* s4 = (const int4*)src;
  const int4* d4 = (const int4*)dst;
  const float4* w4 = (const float4*)ew;
  for (int j = i; j < E4; j += stride) {
    int4 s = s4[j]; int4 d = d4[j]; float4 w = w4[j];
    unsafeAtomicAdd(&h_out[d.x], h_in[s.x] * log1pf(w.x));
    unsafeAtomicAdd(&h_out[d.y], h_in[s.y] * log1pf(w.y));
    unsafeAtomicAdd(&h_out[d.z], h_in[s.z] * log1pf(w.z));
    unsafeAtomicAdd(&h_out[d.w], h_in[s.w] * log1pf(w.w));
  }
  for (int j = E4 * 4 + i; j < E; j += stride)
    unsafeAtomicAdd(&h_out[dst[j]], h_in[src[j]] * log1pf(ew[j]));
}

__global__ void norm_k(const float* __restrict__ h, float* __restrict__ norms, int N) {
  int g = blockIdx.y;
  const float* hg = h + (size_t)g * N;
  float s = 0.f;
  for (int j = blockIdx.x * blockDim.x + threadIdx.x; j < N; j += gridDim.x * blockDim.x) {
    float v = hg[j]; s += v * v;
  }
  __shared__ float sm[4];
  for (int o = 32; o > 0; o >>= 1) s += __shfl_down(s, o, 64);
  if ((threadIdx.x & 63) == 0) sm[threadIdx.x >> 6] = s;
  __syncthreads();
  if (threadIdx.x == 0) {
    float t = 0.f;
    for (int w = 0; w < (int)(blockDim.x >> 6); ++w) t += sm[w];
    unsafeAtomicAdd(&norms[g], t);
  }
}

__global__ void scale_k(const float* __restrict__ norms, float* __restrict__ h_next,
                        float* __restrict__ h_cur, int N) {
  int g = blockIdx.y;
  float inv = 1.0f / sqrtf(norms[g]);
  size_t off = (size_t)g * N;
  for (int j = blockIdx.x * blockDim.x + threadIdx.x; j < N; j += gridDim.x * blockDim.x) {
    h_cur[off + j] = h_next[off + j] * inv;
    h_next[off + j] = 0.f;
  }
}

// ============================ shared epilogue ============================
__device__ __forceinline__ float blk_red(float t, float* sm, int nw) {
  for (int o = 32; o > 0; o >>= 1) t += __shfl_down(t, o, 64);
  if ((threadIdx.x & 63) == 0) sm[threadIdx.x >> 6] = t;
  __syncthreads();
  float r = 0.f;
  for (int w = 0; w < nw; ++w) r += sm[w];
  __syncthreads();
  return r;
}

__global__ void final_k(const float* __restrict__ h, const float* __restrict__ nsq,
                        const int* __restrict__ dm,
                        const float* __restrict__ fc_w, const float* __restrict__ fc_b,
                        float* __restrict__ out, int N, int M) {
  extern __shared__ float v[];
  __shared__ float sm[16];
  int b = blockIdx.x;
  int nw = blockDim.x >> 6;
  float inv = nsq ? 1.0f / sqrtf(nsq[b]) : 1.0f;
  const float* hb = h + (size_t)b * N;
  for (int m = threadIdx.x; m < M; m += blockDim.x) v[m] = hb[dm[m]] * inv;
  __syncthreads();

  float cnt = 0.f, sum = 0.f;
  for (int m = threadIdx.x; m < M; m += blockDim.x) {
    float xv = v[m];
    if (xv != 0.f) { cnt += 1.f; sum += xv; }
  }
  float totalSum = blk_red(sum, sm, nw);
  float totalCnt = blk_red(cnt, sm, nw);
  float mean = totalCnt > 0.f ? totalSum / totalCnt : 0.f;

  float ssq = 0.f;
  for (int m = threadIdx.x; m < M; m += blockDim.x) {
    float xv = v[m];
    if (xv != 0.f) { float d = xv - mean; ssq += d * d; }
  }
  float totalSsq = blk_red(ssq, sm, nw);

  float denom = totalCnt - 1.f;
  if (denom < 1.f) denom = 1.f;
  float stdv = sqrtf(totalSsq / denom) + 1e-5f;

  float ps = 0.f;
  for (int m = threadIdx.x; m < M; m += blockDim.x) {
    float xv = v[m];
    if (xv != 0.f) ps += (xv - mean) / stdv;
  }
  float pooled = blk_red(ps, sm, nw) / (float)M;
  if (threadIdx.x == 0) {
    float o = pooled * fc_w[0] + fc_b[0];
    out[b] = o > 0.f ? o : 0.f;
  }
}

extern "C" void kernel_launch(void* const* d_in, const int* in_sizes, int n_in,
                              void* d_out, int out_size, void* d_ws, size_t ws_size,
                              hipStream_t stream) {
  const float* x    = (const float*)d_in[0];
  const float* ew   = (const float*)d_in[1];
  const int*   src  = (const int*)d_in[2];
  const int*   dst  = (const int*)d_in[3];
  const int*   dm   = (const int*)d_in[4];
  const float* fc_w = (const float*)d_in[5];
  const float* fc_b = (const float*)d_in[6];

  const int BN = in_sizes[0];   // 400000
  const int E  = in_sizes[1];   // 8000000
  const int M  = in_sizes[4];   // 2048
  const int N  = BN / GB;

  const bool shapes_ok = (BN == GB * GN) && (E == EDGES);

  // ---- layout (exact-packed recs; REQ = 89,449,472 <= 94,364,672 floor) ----
  const size_t recs_b = (size_t)(EDGES + 4096) * 8;          // 64,032,768
  const size_t part_b = (size_t)GB * NBUCK * NBUCK * BW * 4; // 22,151,168
  const size_t buf_b  = (size_t)BN * 4;                      // 1,600,000
  const size_t misc_b = 65536;
  const size_t REQ = recs_b + part_b + 2 * buf_b + misc_b;

  if (shapes_ok && ws_size >= REQ) {
    uint2* recs     = (uint2*)d_ws;
    float* partials = (float*)((char*)d_ws + recs_b);
    float* bufA     = (float*)((char*)partials + part_b);
    float* bufB     = (float*)((char*)bufA + buf_b);
    char*  misc     = (char*)bufB + buf_b;
    int*   gcur     = (int*)misc;                  // [NB2]
    int*   cntp     = gcur + NB2;                  // [NB2]
    int*   basea    = cntp + NB2;                  // [NB2+1]
    float* nsq      = (float*)(basea + NB2 + 8);   // [GB]

    z_k<<<1, 256, 0, stream>>>(gcur, cntp, nsq);
    count_k<<<NBLKH, 256, 0, stream>>>(src, dst, cntp);
    scan_k<<<1, 256, 0, stream>>>(cntp, basea);
    fscatter_k<<<NBLKH, 256, 0, stream>>>(src, dst, ew, basea, gcur, recs);

    int rgrid = (BN / 4 + 255) / 256;   // 391
    dim3 agrid(NBUCK, GB * NBUCK);      // (13, 104)
    accum_k<<<agrid, 256, 0, stream>>>(recs, basea, cntp, x, partials);
    reduce_k<<<rgrid, 256, 0, stream>>>(partials, bufA, nullptr);
    accum_k<<<agrid, 256, 0, stream>>>(recs, basea, cntp, bufA, partials);
    reduce_k<<<rgrid, 256, 0, stream>>>(partials, bufB, nullptr);
    accum_k<<<agrid, 256, 0, stream>>>(recs, basea, cntp, bufB, partials);
    reduce_k<<<rgrid, 256, 0, stream>>>(partials, bufA, nsq);   // fused final ssq

    final_k<<<GB, 512, M * sizeof(float), stream>>>(bufA, nsq, dm, fc_w, fc_b,
                                                    (float*)d_out, N, M);
    return;
  }

  // ---- v1 fallback ----
  float* h_cur  = (float*)d_ws;
  float* h_next = h_cur + BN;
  float* norms  = h_next + BN;
  const int threads = 256;
  init_k<<<(BN + threads - 1) / threads, threads, 0, stream>>>(x, h_cur, h_next,
                                                               norms, BN, NP * GB);
  int E4 = E / 4;
  int edgeBlocks = (E4 + threads - 1) / threads;
  dim3 ngrid((N + threads * 8 - 1) / (threads * 8), GB);
  for (int p = 0; p < NP; ++p) {
    edge_k<<<edgeBlocks, threads, 0, stream>>>(src, dst, ew, h_cur, h_next, E4, E);
    norm_k<<<ngrid, threads, 0, stream>>>(h_next, norms + p * GB, N);
    scale_k<<<ngrid, threads, 0, stream>>>(norms + p * GB, h_next, h_cur, N);
  }
  final_k<<<GB, 256, M * sizeof(float), stream>>>(h_cur, nullptr, dm, fc_w, fc_b,
                                                  (float*)d_out, N, M);
}

// Round 2
// 339.234 us; speedup vs baseline: 1.3010x; 1.3010x over previous
//
#include <hip/hip_runtime.h>
#include <math.h>

// Problem constants (fixed by setup_inputs): B=8 graphs, N=50000 nodes/graph,
// EPG=1e6 edges/graph, E=8e6, M=2048, num_passes=3.
#define GB    8
#define GN    50000
#define EPG   1000000
#define EDGES (GB*EPG)
#define NP    3

#define BW     4096           // dst-bucket width (floats) -> 16KB LDS accum
#define NBUCK  13             // ceil(50000/4096); last bucket width 848
#define NBINS  (GB*NBUCK)     // 104
#define CAP    89088          // fixed recs capacity per bin (mean 81920, +26σ)
#define CPB    10             // chunk-blocks per bin -> 1040 accum blocks
#define STRIPE 2000           // edges per binning block (16KB LDS sort buffer)
#define NQ     (STRIPE/4)     // 500 quads
#define NBLKH  (EDGES/STRIPE) // 4000 binning blocks
#define BPG    (EPG/STRIPE)   // 500 blocks per graph
#define SRCMASK 0x7FFFFu      // src fits 19 bits (BN=400000 < 2^19)

// ============================ fast path ============================
// 1. z_k      : zero gcur + bufA/B/C
// 2. fscatter : 13-dst-bin rank+reserve, LDS-SORT the stripe by bin, then
//               write out per-bin runs COALESCED (fixes the 64-way scattered
//               store pattern seen in rocprof: WRITE_SIZE amplification).
//               rec.x = (dst_in_bucket << 19) | src_global, rec.y = log1pf(w)
// 3. accum x3 : one (bin,chunk) per block; LDS-accumulate; epilogue adds acc
//               straight into hout via unsafeAtomicAdd (no partials/reduce).
// 4. final_k  : fused per-graph L2 norm (telescoped) + mask/normalize/pool.

__global__ void z_k(int* __restrict__ gcur, float4* __restrict__ a,
                    float4* __restrict__ b, float4* __restrict__ c) {
  int i = blockIdx.x * 256 + threadIdx.x;
  float4 z = {0.f, 0.f, 0.f, 0.f};
  if (i < (GB * GN) / 4) { a[i] = z; b[i] = z; c[i] = z; }
  if (blockIdx.x == 0 && threadIdx.x < NBINS) gcur[threadIdx.x] = 0;
}

// Fused bin+rank+reserve+LDS-sort+coalesced-scatter:
//  phase 1: per-edge rank within (block,bin) via LDS hist (ranks in regs)
//  phase 2: reserve per-bin global offset (13 atomics) + local prefix scan
//  phase 3a: re-read stripe (cache-resident), ds_write record to sorted slot
//  phase 3b: per-bin runs written to global with consecutive threads ->
//            coalesced contiguous uint2 stores (~154 recs = 1.2KB per run).
// After the kernel, gcur[bin] == bin's record count (used by accum).
__global__ __launch_bounds__(256) void fscatter_k(
    const int* __restrict__ src, const int* __restrict__ dst,
    const float* __restrict__ ew, int* __restrict__ gcur,
    uint2* __restrict__ recs) {
  __shared__ int lh[NBUCK];     // per-bin count
  __shared__ int lsb[NBUCK];    // local sorted base (excl scan of lh)
  __shared__ int lbg[NBUCK];    // reserved global base
  __shared__ uint2 srt[STRIPE]; // 16KB sorted record buffer
  if (threadIdx.x < NBUCK) lh[threadIdx.x] = 0;
  __syncthreads();
  int blk = blockIdx.x;
  int s0 = blk * STRIPE;
  int g = blk / BPG;                  // stripe never crosses a graph
  int base = g * GN, gb = g * NBUCK;
  const int4* d4 = (const int4*)(dst + s0);
  const int4* s4 = (const int4*)(src + s0);
  const float4* w4 = (const float4*)(ew + s0);

  int rk[8];
#pragma unroll
  for (int u = 0; u < 2; ++u) {
    int q = threadIdx.x + 256 * u;
    if (q < NQ) {
      int4 d = d4[q];
      rk[4 * u + 0] = atomicAdd(&lh[(d.x - base) >> 12], 1);
      rk[4 * u + 1] = atomicAdd(&lh[(d.y - base) >> 12], 1);
      rk[4 * u + 2] = atomicAdd(&lh[(d.z - base) >> 12], 1);
      rk[4 * u + 3] = atomicAdd(&lh[(d.w - base) >> 12], 1);
    }
  }
  __syncthreads();
  if (threadIdx.x < NBUCK) {
    int c = lh[threadIdx.x];
    lbg[threadIdx.x] = c ? atomicAdd(&gcur[gb + threadIdx.x], c) : 0;
    int s = 0;
    for (int j = 0; j < threadIdx.x; ++j) s += lh[j];
    lsb[threadIdx.x] = s;
  }
  __syncthreads();
#pragma unroll
  for (int u = 0; u < 2; ++u) {
    int q = threadIdx.x + 256 * u;
    if (q < NQ) {
      int4 d = d4[q]; int4 s = s4[q]; float4 w = w4[q];
      int dv[4] = {d.x, d.y, d.z, d.w};
      int sv[4] = {s.x, s.y, s.z, s.w};
      float wv[4] = {w.x, w.y, w.z, w.w};
#pragma unroll
      for (int k = 0; k < 4; ++k) {
        int dl = dv[k] - base;
        int bin = dl >> 12;
        srt[lsb[bin] + rk[4 * u + k]] =
            make_uint2(((unsigned)(dl & (BW - 1)) << 19) | (unsigned)sv[k],
                       __float_as_uint(log1pf(wv[k])));
      }
    }
  }
  __syncthreads();
  for (int b = 0; b < NBUCK; ++b) {
    int cnt = lh[b];
    int lo = lsb[b];
    uint2* dp = recs + (size_t)(gb + b) * CAP + lbg[b];
    for (int i = threadIdx.x; i < cnt; i += 256) dp[i] = srt[lo + i];
  }
}

// One (bin, chunk) per block: LDS-accumulate this bin's edges; 2x uint4/iter.
// Epilogue: atomic-add acc into hout (pre-zeroed) -- no partials, no reduce.
__global__ __launch_bounds__(256) void accum_k(
    const uint2* __restrict__ recs, const int* __restrict__ cnt,
    const float* __restrict__ hin, float* __restrict__ hout) {
  __shared__ float acc[BW];
  int c = blockIdx.x;               // chunk [0,CPB)
  int bin = blockIdx.y;             // [0,NBINS)
  float4 z = {0.f, 0.f, 0.f, 0.f};
  float4* a4 = (float4*)acc;
  for (int i = threadIdx.x; i < BW / 4; i += 256) a4[i] = z;
  int len = cnt[bin];
  int chunk = ((len + CPB - 1) / CPB + 1) & ~1;   // even chunk
  int lo = c * chunk;
  int hi = lo + chunk;
  if (lo > len) lo = len;
  if (hi > len) hi = len;
  const uint2* rb = recs + (size_t)bin * CAP;
  __syncthreads();
  int rem = hi - lo;                // lo even (CAP even, chunk even)
  if (rem < 0) rem = 0;
  int np = rem >> 1;                // uint4 count (2 recs each)
  const uint4* rp = (const uint4*)(rb + lo);
  int p = threadIdx.x;
  for (; p + 256 < np; p += 512) {
    uint4 r0 = rp[p];
    uint4 r1 = rp[p + 256];
    float a0 = hin[r0.x & SRCMASK] * __uint_as_float(r0.y);
    float a1 = hin[r0.z & SRCMASK] * __uint_as_float(r0.w);
    float a2 = hin[r1.x & SRCMASK] * __uint_as_float(r1.y);
    float a3 = hin[r1.z & SRCMASK] * __uint_as_float(r1.w);
    atomicAdd(&acc[r0.x >> 19], a0);
    atomicAdd(&acc[r0.z >> 19], a1);
    atomicAdd(&acc[r1.x >> 19], a2);
    atomicAdd(&acc[r1.z >> 19], a3);
  }
  if (p < np) {
    uint4 r0 = rp[p];
    atomicAdd(&acc[r0.x >> 19], hin[r0.x & SRCMASK] * __uint_as_float(r0.y));
    atomicAdd(&acc[r0.z >> 19], hin[r0.z & SRCMASK] * __uint_as_float(r0.w));
  }
  if ((rem & 1) && threadIdx.x == 0) {
    uint2 a = rb[hi - 1];
    atomicAdd(&acc[a.x >> 19], hin[a.x & SRCMASK] * __uint_as_float(a.y));
  }
  __syncthreads();
  int g = bin / NBUCK, bucket = bin - g * NBUCK;
  int sw = GN - bucket * BW; if (sw > BW) sw = BW;   // 848 for bucket 12
  float* ho = hout + (size_t)g * GN + (size_t)bucket * BW;
  for (int i = threadIdx.x; i < sw; i += 256) {
    float v = acc[i];
    if (v != 0.f) unsafeAtomicAdd(&ho[i], v);
  }
}

// ============================ v1 fallback ============================

__global__ void init_k(const float* __restrict__ x, float* __restrict__ h_cur,
                       float* __restrict__ h_next, float* __restrict__ norms,
                       int BN, int n_norms) {
  int i = blockIdx.x * blockDim.x + threadIdx.x;
  int stride = gridDim.x * blockDim.x;
  for (int j = i; j < BN; j += stride) { h_cur[j] = x[j]; h_next[j] = 0.f; }
  if (i < n_norms) norms[i] = 0.f;
}

__global__ void edge_k(const int* __restrict__ src, const int* __restrict__ dst,
                       const float* __restrict__ ew, const float* __restrict__ h_in,
                       float* __restrict__ h_out, int E4, int E) {
  int i = blockIdx.x * blockDim.x + threadIdx.x;
  int stride = gridDim.x * blockDim.x;
  const int4* s4 = (const int4*)src;
  const int4* d4 = (const int4*)dst;
  const float4* w4 = (const float4*)ew;
  for (int j = i; j < E4; j += stride) {
    int4 s = s4[j]; int4 d = d4[j]; float4 w = w4[j];
    unsafeAtomicAdd(&h_out[d.x], h_in[s.x] * log1pf(w.x));
    unsafeAtomicAdd(&h_out[d.y], h_in[s.y] * log1pf(w.y));
    unsafeAtomicAdd(&h_out[d.z], h_in[s.z] * log1pf(w.z));
    unsafeAtomicAdd(&h_out[d.w], h_in[s.w] * log1pf(w.w));
  }
  for (int j = E4 * 4 + i; j < E; j += stride)
    unsafeAtomicAdd(&h_out[dst[j]], h_in[src[j]] * log1pf(ew[j]));
}

__global__ void norm_k(const float* __restrict__ h, float* __restrict__ norms, int N) {
  int g = blockIdx.y;
  const float* hg = h + (size_t)g * N;
  float s = 0.f;
  for (int j = blockIdx.x * blockDim.x + threadIdx.x; j < N; j += gridDim.x * blockDim.x) {
    float v = hg[j]; s += v * v;
  }
  __shared__ float sm[4];
  for (int o = 32; o > 0; o >>= 1) s += __shfl_down(s, o, 64);
  if ((threadIdx.x & 63) == 0) sm[threadIdx.x >> 6] = s;
  __syncthreads();
  if (threadIdx.x == 0) {
    float t = 0.f;
    for (int w = 0; w < (int)(blockDim.x >> 6); ++w) t += sm[w];
    unsafeAtomicAdd(&norms[g], t);
  }
}

__global__ void scale_k(const float* __restrict__ norms, float* __restrict__ h_next,
                        float* __restrict__ h_cur, int N) {
  int g = blockIdx.y;
  float inv = 1.0f / sqrtf(norms[g]);
  size_t off = (size_t)g * N;
  for (int j = blockIdx.x * blockDim.x + threadIdx.x; j < N; j += gridDim.x * blockDim.x) {
    h_cur[off + j] = h_next[off + j] * inv;
    h_next[off + j] = 0.f;
  }
}

// ============================ shared epilogue ============================
__device__ __forceinline__ float blk_red(float t, float* sm, int nw) {
  for (int o = 32; o > 0; o >>= 1) t += __shfl_down(t, o, 64);
  if ((threadIdx.x & 63) == 0) sm[threadIdx.x >> 6] = t;
  __syncthreads();
  float r = 0.f;
  for (int w = 0; w < nw; ++w) r += sm[w];
  __syncthreads();
  return r;
}

// do_norm: fast path passes 1 (h unnormalized; fused per-graph L2 norm).
__global__ void final_k(const float* __restrict__ h, const int* __restrict__ dm,
                        const float* __restrict__ fc_w, const float* __restrict__ fc_b,
                        float* __restrict__ out, int N, int M, int do_norm) {
  extern __shared__ float v[];
  __shared__ float sm[16];
  int b = blockIdx.x;
  int nw = blockDim.x >> 6;
  const float* hb = h + (size_t)b * N;
  float inv = 1.0f;
  if (do_norm) {
    const float4* h4 = (const float4*)hb;
    float s = 0.f;
    for (int i = threadIdx.x; i < N / 4; i += blockDim.x) {
      float4 t = h4[i];
      s += t.x * t.x + t.y * t.y + t.z * t.z + t.w * t.w;
    }
    for (int i = N & ~3; i < N; ++i)   // tail (N%4==0 here, no-op)
      if (threadIdx.x == 0) s += hb[i] * hb[i];
    float tot = blk_red(s, sm, nw);
    inv = 1.0f / sqrtf(tot);
  }
  for (int m = threadIdx.x; m < M; m += blockDim.x) v[m] = hb[dm[m]] * inv;
  __syncthreads();

  float cnt = 0.f, sum = 0.f;
  for (int m = threadIdx.x; m < M; m += blockDim.x) {
    float xv = v[m];
    if (xv != 0.f) { cnt += 1.f; sum += xv; }
  }
  float totalSum = blk_red(sum, sm, nw);
  float totalCnt = blk_red(cnt, sm, nw);
  float mean = totalCnt > 0.f ? totalSum / totalCnt : 0.f;

  float ssq = 0.f;
  for (int m = threadIdx.x; m < M; m += blockDim.x) {
    float xv = v[m];
    if (xv != 0.f) { float d = xv - mean; ssq += d * d; }
  }
  float totalSsq = blk_red(ssq, sm, nw);

  float denom = totalCnt - 1.f;
  if (denom < 1.f) denom = 1.f;
  float stdv = sqrtf(totalSsq / denom) + 1e-5f;

  float ps = 0.f;
  for (int m = threadIdx.x; m < M; m += blockDim.x) {
    float xv = v[m];
    if (xv != 0.f) ps += (xv - mean) / stdv;
  }
  float pooled = blk_red(ps, sm, nw) / (float)M;
  if (threadIdx.x == 0) {
    float o = pooled * fc_w[0] + fc_b[0];
    out[b] = o > 0.f ? o : 0.f;
  }
}

extern "C" void kernel_launch(void* const* d_in, const int* in_sizes, int n_in,
                              void* d_out, int out_size, void* d_ws, size_t ws_size,
                              hipStream_t stream) {
  const float* x    = (const float*)d_in[0];
  const float* ew   = (const float*)d_in[1];
  const int*   src  = (const int*)d_in[2];
  const int*   dst  = (const int*)d_in[3];
  const int*   dm   = (const int*)d_in[4];
  const float* fc_w = (const float*)d_in[5];
  const float* fc_b = (const float*)d_in[6];

  const int BN = in_sizes[0];   // 400000
  const int E  = in_sizes[1];   // 8000000
  const int M  = in_sizes[4];   // 2048
  const int N  = BN / GB;

  const bool shapes_ok = (BN == GB * GN) && (E == EDGES);

  // ---- layout (fixed-capacity recs; REQ ~ 79 MB <= verified floor) ----
  const size_t recs_b = (size_t)NBINS * CAP * 8;   // 74,121,216
  const size_t buf_b  = (size_t)BN * 4;            // 1,600,000
  const size_t misc_b = 4096;
  const size_t REQ = recs_b + 3 * buf_b + misc_b;

  if (shapes_ok && ws_size >= REQ) {
    uint2* recs = (uint2*)d_ws;
    float* bufA = (float*)((char*)d_ws + recs_b);
    float* bufB = bufA + BN;
    float* bufC = bufB + BN;
    int*   gcur = (int*)(bufC + BN);               // [NBINS]; == counts after fscatter

    z_k<<<(BN / 4 + 255) / 256, 256, 0, stream>>>(gcur, (float4*)bufA,
                                                  (float4*)bufB, (float4*)bufC);
    fscatter_k<<<NBLKH, 256, 0, stream>>>(src, dst, ew, gcur, recs);

    dim3 agrid(CPB, NBINS);
    accum_k<<<agrid, 256, 0, stream>>>(recs, gcur, x, bufA);
    accum_k<<<agrid, 256, 0, stream>>>(recs, gcur, bufA, bufB);
    accum_k<<<agrid, 256, 0, stream>>>(recs, gcur, bufB, bufC);

    final_k<<<GB, 512, M * sizeof(float), stream>>>(bufC, dm, fc_w, fc_b,
                                                    (float*)d_out, N, M, 1);
    return;
  }

  // ---- v1 fallback ----
  float* h_cur  = (float*)d_ws;
  float* h_next = h_cur + BN;
  float* norms  = h_next + BN;
  const int threads = 256;
  init_k<<<(BN + threads - 1) / threads, threads, 0, stream>>>(x, h_cur, h_next,
                                                               norms, BN, NP * GB);
  int E4 = E / 4;
  int edgeBlocks = (E4 + threads - 1) / threads;
  dim3 ngrid((N + threads * 8 - 1) / (threads * 8), GB);
  for (int p = 0; p < NP; ++p) {
    edge_k<<<edgeBlocks, threads, 0, stream>>>(src, dst, ew, h_cur, h_next, E4, E);
    norm_k<<<ngrid, threads, 0, stream>>>(h_next, norms + p * GB, N);
    scale_k<<<ngrid, threads, 0, stream>>>(norms + p * GB, h_next, h_cur, N);
  }
  final_k<<<GB, 256, M * sizeof(float), stream>>>(h_cur, dm, fc_w, fc_b,
                                                  (float*)d_out, N, M, 0);
}